// Round 4
// baseline (162.056 us; speedup 1.0000x reference)
//
#include <hip/hip_runtime.h>
#include <math.h>

#define NB 8192
#define DK 128
#define NTILES 64          // 128-row tiles
#define NCHUNK 32          // 256-col chunks (2 tiles)
#define NBLK 1056          // sum over ti of (32 - ti/2)
#define JT 64              // cols per LDS subtile
#define NT 4               // subtiles per chunk
#define BSTRH 136          // B LDS row stride in bf16 (272 B) -> conflict-free b128
#define NSLOT 96           // 64 col-tile slots + 32 row-chunk slots
#define SENT -1.7e38f

typedef __attribute__((ext_vector_type(8))) short short8;
typedef __attribute__((ext_vector_type(16))) float float16;

__device__ inline unsigned short f2bf(float f) {
    unsigned int x = __float_as_uint(f);
    unsigned int r = (x + 0x7fffu + ((x >> 16) & 1u)) >> 16;
    return (unsigned short)r;
}

// ------- normalize -> bf16, packed meta, sentinel-fill partials, zero accum -----
__global__ void norm_kernel(const float* __restrict__ emb, const int* __restrict__ labels,
                            const int* __restrict__ groups, unsigned short* __restrict__ xnb,
                            int* __restrict__ meta, float2* __restrict__ part,
                            float* __restrict__ accum, int* __restrict__ ticket) {
    int row  = blockIdx.x * 4 + (threadIdx.x >> 6);
    int lane = threadIdx.x & 63;
    float2 v = ((const float2*)(emb + (size_t)row * DK))[lane];
    float ss = v.x * v.x + v.y * v.y;
#pragma unroll
    for (int off = 32; off; off >>= 1) ss += __shfl_xor(ss, off, 64);
    float inv = 1.0f / fmaxf(sqrtf(ss), 1e-12f);
    ushort2 o;
    o.x = f2bf(v.x * inv);
    o.y = f2bf(v.y * inv);
    ((ushort2*)(xnb + (size_t)row * DK))[lane] = o;
    if (lane == 0) meta[row] = (labels[row] << 8) | groups[row];

    // sentinel-fill part[96][NB]: 786432 float2 over 524288 threads
    size_t g = (size_t)blockIdx.x * 256 + threadIdx.x;
    float2 snt; snt.x = SENT; snt.y = SENT;
    part[g] = snt;
    if (g < (size_t)NSLOT * NB - 524288) part[g + 524288] = snt;

    if (blockIdx.x == 0 && threadIdx.x == 0) {
        accum[0] = 0.0f; accum[1] = 0.0f; ticket[0] = 0;
    }
}

// ------- strip-triangular MFMA gram + two-sided mining --------------------------
// Encoded similarity space (proven):
//   -t = (same_label? 8:0) - s   feeds apn (row side) and col side
//    v = s - 8*sl + 4*sg         feeds anc (row side) and col side
// C layout (verified): col = lane&31, row = (reg&3) + 8*(reg>>2) + 4*(lane>>5)
//
// Blocks (ti, c) with c >= ti>>1: rows = tile ti (128), cols = chunk c (256).
// part slots: [0..63] col-side keyed by ti (unique writer per (ti,c) column range)
//             [64..95] row-side keyed by c (unique writer per (ti,c) row range)
// Valid slots per anchor i (tile t): col tv <= (t|1), row 64+c for c >= t>>1.
// All other slots hold SENT from norm_kernel. Sub-diagonal duplicate compute
// (~1.5%) is harmless under max.
__global__ __launch_bounds__(256, 3) void mine_strip(
    const unsigned short* __restrict__ xnb, const int* __restrict__ meta,
    float2* __restrict__ part) {
    __shared__ unsigned short Bs[2][JT * BSTRH];   // 2 x 17408 B
    __shared__ float colred[2][4][8][32];          // 8 KB: [arr][wave][q][col]

    // decode blockIdx.x -> (ti, c): row-pair groups u = ti>>1, 2*(32-u) blocks each
    int bid = blockIdx.x;
    int u = 0;
    while (bid >= 2 * (NCHUNK - u)) { bid -= 2 * (NCHUNK - u); u++; }
    const int cnt = NCHUNK - u;
    const int sel = (bid >= cnt) ? 1 : 0;
    const int ti  = 2 * u + sel;
    const int c   = u + (sel ? bid - cnt : bid);

    const int tid  = threadIdx.x;
    const int w    = tid >> 6;
    const int lane = tid & 63;
    const int half = lane >> 5;
    const int l31  = lane & 31;
    const int jbase = c * 256;
    const int irow  = ti * 128 + w * 32;

    // A fragments, full K=128 resident (8 x short8 = 64 VGPRs)
    short8 afrag[8];
#pragma unroll
    for (int ks = 0; ks < 8; ks++)
        afrag[ks] = *(const short8*)(xnb + (size_t)(irow + l31) * DK + ks * 16 + half * 8);

    int metaI[16];
    float apn[16], anc[16];
#pragma unroll
    for (int reg = 0; reg < 16; reg++) {
        int r = (reg & 3) + 8 * (reg >> 2) + 4 * half;
        metaI[reg] = meta[irow + r];
        apn[reg] = -1e9f; anc[reg] = -1e9f;
    }

    // prologue: stage subtile 0 (rows jbase .. jbase+63)
#pragma unroll
    for (int s = 0; s < 4; s++) {
        int chunk = tid + s * 256;
        int row = chunk >> 4, k4 = chunk & 15;
        *(uint4*)&Bs[0][row * BSTRH + k4 * 8] =
            *(const uint4*)(xnb + (size_t)(jbase + row) * DK + k4 * 8);
    }
    __syncthreads();

#pragma unroll
    for (int jt = 0; jt < NT; jt++) {
        const int cur = jt & 1;
        const int j0  = jbase + jt * JT;

        // prefetch next subtile into registers (overlaps with compute below)
        uint4 pre[4];
        if (jt + 1 < NT) {
            const int j0n = j0 + JT;
#pragma unroll
            for (int s = 0; s < 4; s++) {
                int chunk = tid + s * 256;
                int row = chunk >> 4, k4 = chunk & 15;
                pre[s] = *(const uint4*)(xnb + (size_t)(j0n + row) * DK + k4 * 8);
            }
        }

        int mjc[2];
        mjc[0] = meta[j0 + l31];
        mjc[1] = meta[j0 + 32 + l31];

        float apnC2[2], ancC2[2];                 // col-side accums, this jt only
#pragma unroll
        for (int ct = 0; ct < 2; ct++) {
            float16 cc;
#pragma unroll
            for (int e = 0; e < 16; e++) cc[e] = 0.0f;

            const int bro = ct * 32 + l31;
#pragma unroll
            for (int ks = 0; ks < 8; ks++) {
                short8 b = *(const short8*)&Bs[cur][bro * BSTRH + ks * 16 + half * 8];
                cc = __builtin_amdgcn_mfma_f32_32x32x16_bf16(afrag[ks], b, cc, 0, 0, 0);
            }

            const int mj = mjc[ct];
            float ca = -1e9f, cn = -1e9f;
#pragma unroll
            for (int reg = 0; reg < 16; reg++) {
                float s = cc[reg];
                int x = metaI[reg] ^ mj;
                bool sl = (unsigned)x < 0x100u;   // same label
                float t8 = s - 8.0f;
                float t  = sl ? t8 : s;           // t = s - (sl?8:0)
                apn[reg] = fmaxf(apn[reg], -t);   // row-side (neg modifier free)
                ca = fmaxf(ca, -t);               // col-side
                bool sg = (x & 0xFFu) == 0u;      // same group
                float t4 = t + 4.0f;
                float v  = sg ? t4 : t;           // + (sg?4:0)
                anc[reg] = fmaxf(anc[reg], v);
                cn = fmaxf(cn, v);
            }
            apnC2[ct] = ca; ancC2[ct] = cn;
        }

        // fold col-side accums for this jt's two 32-col groups into LDS
#pragma unroll
        for (int ct2 = 0; ct2 < 2; ct2++) {
            float a = fmaxf(apnC2[ct2], __shfl_xor(apnC2[ct2], 32, 64));
            float n = fmaxf(ancC2[ct2], __shfl_xor(ancC2[ct2], 32, 64));
            if (half == 0) {
                colred[0][w][jt * 2 + ct2][l31] = a;
                colred[1][w][jt * 2 + ct2][l31] = n;
            }
        }

        // write prefetched subtile into the other buffer
        if (jt + 1 < NT) {
#pragma unroll
            for (int s = 0; s < 4; s++) {
                int chunk = tid + s * 256;
                int row = chunk >> 4, k4 = chunk & 15;
                *(uint4*)&Bs[cur ^ 1][row * BSTRH + k4 * 8] = pre[s];
            }
        }
        __syncthreads();
    }

    // ---- row side: butterfly reduce across the 32 column-lanes, slot 64+c ----
#pragma unroll
    for (int reg = 0; reg < 16; reg++) {
#pragma unroll
        for (int off = 16; off; off >>= 1) {
            apn[reg] = fmaxf(apn[reg], __shfl_xor(apn[reg], off, 64));
            anc[reg] = fmaxf(anc[reg], __shfl_xor(anc[reg], off, 64));
        }
    }
    if (l31 == 0) {
#pragma unroll
        for (int reg = 0; reg < 16; reg++) {
            int r = (reg & 3) + 8 * (reg >> 2) + 4 * half;
            float2 o; o.x = apn[reg]; o.y = anc[reg];
            part[(size_t)(64 + c) * NB + (irow + r)] = o;
        }
    }

    // ---- col side: cross-wave reduce of colred, slot ti (256 cols, 1/thread) ----
    // (final __syncthreads in the jt loop guarantees all folds are visible)
    {
        int q = tid >> 5, l = tid & 31;
        float ma = -1e9f, mn = -1e9f;
#pragma unroll
        for (int wv = 0; wv < 4; wv++) {
            ma = fmaxf(ma, colred[0][wv][q][l]);
            mn = fmaxf(mn, colred[1][wv][q][l]);
        }
        float2 o; o.x = ma; o.y = mn;
        part[(size_t)ti * NB + (jbase + tid)] = o;
    }
}

// ------- combine: 96 static slots per anchor + ticketed finalize ---------------
__global__ void combine_kernel(const float2* __restrict__ part,
                               float* __restrict__ accum, int* __restrict__ ticket,
                               float* __restrict__ out) {
    int i = blockIdx.x * 64 + threadIdx.x;
    float a0 = -3e38f, a1 = -3e38f, a2 = -3e38f, a3 = -3e38f;
    float n0 = -3e38f, n1 = -3e38f, n2 = -3e38f, n3 = -3e38f;
#pragma unroll
    for (int s = 0; s < NSLOT; s += 4) {
        float2 p0 = part[(size_t)(s + 0) * NB + i];
        float2 p1 = part[(size_t)(s + 1) * NB + i];
        float2 p2 = part[(size_t)(s + 2) * NB + i];
        float2 p3 = part[(size_t)(s + 3) * NB + i];
        a0 = fmaxf(a0, p0.x); n0 = fmaxf(n0, p0.y);
        a1 = fmaxf(a1, p1.x); n1 = fmaxf(n1, p1.y);
        a2 = fmaxf(a2, p2.x); n2 = fmaxf(n2, p2.y);
        a3 = fmaxf(a3, p3.x); n3 = fmaxf(n3, p3.y);
    }
    float apn = fmaxf(fmaxf(a0, a1), fmaxf(a2, a3));
    float anc = fmaxf(fmaxf(n0, n1), fmaxf(n2, n3));

    float anS = (anc > 2.0f) ? anc - 4.0f : anc;
    // loss = anS - (8 - apn) + 0.1 ; suppressed-label values decode to loss <= 0
    float loss = anS + apn - 7.9f;
    float inc = (loss > 0.0f) ? 1.0f : 0.0f;
    float val = inc * loss;

#pragma unroll
    for (int off = 32; off; off >>= 1) {
        val += __shfl_xor(val, off, 64);
        inc += __shfl_xor(inc, off, 64);
    }
    if (threadIdx.x == 0) {
        atomicAdd(&accum[0], val);
        atomicAdd(&accum[1], inc);
        __threadfence();                       // release: accum adds visible device-wide
        int old = atomicAdd(ticket, 1);        // device-scope
        if (old == gridDim.x - 1) {            // last block finalizes
            __threadfence();                   // acquire side
            float total = __hip_atomic_load(&accum[0], __ATOMIC_RELAXED, __HIP_MEMORY_SCOPE_AGENT);
            float cnt   = __hip_atomic_load(&accum[1], __ATOMIC_RELAXED, __HIP_MEMORY_SCOPE_AGENT);
            float r = (cnt > 0.0f) ? total / fmaxf(cnt, 1.0f) : 0.0f;
            if (isnan(r)) r = 0.0f;
            out[0] = r;
        }
    }
}

extern "C" void kernel_launch(void* const* d_in, const int* in_sizes, int n_in,
                              void* d_out, int out_size, void* d_ws, size_t ws_size,
                              hipStream_t stream) {
    const float* emb  = (const float*)d_in[0];
    const int* labels = (const int*)d_in[1];
    const int* groups = (const int*)d_in[2];
    float* out = (float*)d_out;

    unsigned short* xnb = (unsigned short*)d_ws;            // 2 MB
    int*    meta   = (int*)(xnb + (size_t)NB * DK);         // 32 KB
    float2* part   = (float2*)(meta + NB);                  // 6 MB: [96][NB] {apn,anc}
    float*  accum  = (float*)(part + (size_t)NSLOT * NB);   // 2 floats
    int*    ticket = (int*)(accum + 2);                     // 1 int

    norm_kernel<<<NB / 4, 256, 0, stream>>>(emb, labels, groups, xnb, meta, part, accum, ticket);
    mine_strip<<<NBLK, 256, 0, stream>>>(xnb, meta, part);
    combine_kernel<<<128, 64, 0, stream>>>(part, accum, ticket, out);
}

// Round 5
// 101.948 us; speedup vs baseline: 1.5896x; 1.5896x over previous
//
#include <hip/hip_runtime.h>
#include <math.h>

#define NB 8192
#define DK 128
#define TI 128                         // square tile edge (rows == cols)
#define NTILES (NB / TI)               // 64
#define NBLK (NTILES * (NTILES + 1) / 2)  // 2080 upper-triangle blocks
#define JT 64                          // j-cols per LDS tile
#define NT (TI / JT)                   // 2 j-tiles per block
#define BSTRH 136                      // B LDS row stride in bf16 (272 B) -> conflict-free b128
#define NCOMB (NB / 256)               // 32 combine blocks

typedef __attribute__((ext_vector_type(8))) short short8;
typedef __attribute__((ext_vector_type(16))) float float16;

__device__ inline unsigned short f2bf(float f) {
    unsigned int x = __float_as_uint(f);
    unsigned int r = (x + 0x7fffu + ((x >> 16) & 1u)) >> 16;
    return (unsigned short)r;
}

// ---------------- normalize -> bf16, packed meta, and zero accum/ticket ---------
__global__ void norm_kernel(const float* __restrict__ emb, const int* __restrict__ labels,
                            const int* __restrict__ groups, unsigned short* __restrict__ xnb,
                            int* __restrict__ meta, float* __restrict__ accum,
                            int* __restrict__ ticket) {
    int row  = blockIdx.x * 4 + (threadIdx.x >> 6);
    int lane = threadIdx.x & 63;
    float2 v = ((const float2*)(emb + (size_t)row * DK))[lane];
    float ss = v.x * v.x + v.y * v.y;
#pragma unroll
    for (int off = 32; off; off >>= 1) ss += __shfl_xor(ss, off, 64);
    float inv = 1.0f / fmaxf(sqrtf(ss), 1e-12f);
    ushort2 o;
    o.x = f2bf(v.x * inv);
    o.y = f2bf(v.y * inv);
    ((ushort2*)(xnb + (size_t)row * DK))[lane] = o;
    if (lane == 0) meta[row] = (labels[row] << 8) | groups[row];
    if (blockIdx.x == 0 && threadIdx.x == 0) {
        accum[0] = 0.0f; accum[1] = 0.0f; ticket[0] = 0;
    }
}

// ---------------- symmetric (upper-triangle) MFMA gram + two-sided mining -------
// Encoded similarity space (proven):
//   -t = (same_label? 8:0) - s   feeds apn (row) AND apn_col (col side, symmetric)
//    v = s - 8*sl + 4*sg         feeds anc (row) AND anc_col
// C layout (verified): col = lane&31, row = (reg&3) + 8*(reg>>2) + 4*(lane>>5)
//
// Unified partial array part[64][NB] (float2 {apn, anc}):
//   row-side of block (ti,tj) writes (slot tj, rows of tile ti)   [slot >= rowtile]
//   col-side of block (ti,tj), ti<tj, writes (slot ti, rows of tile tj) [slot < rowtile]
//   diagonal blocks skip col-side (identical to row-side by symmetry)
// => every (slot, row) written exactly once; all 64 slots valid for every row.
//
// SINGLE-buffered LDS, no register prefetch: peak VGPR pressure ~155 fits the
// __launch_bounds__(256,3) budget (~170). Round-4 counters proved the prefetch
// registers pushed us over the spill cliff (VGPR_Count=84, 230 MB scratch).
__global__ __launch_bounds__(256, 3) void mine_tri(
    const unsigned short* __restrict__ xnb, const int* __restrict__ meta,
    float2* __restrict__ part) {
    __shared__ unsigned short Bs[JT * BSTRH];      // 17408 B, single buffer

    // map blockIdx.x -> (ti, tj), ti <= tj
    int bid = blockIdx.x;
    int ti = 0;
    while (bid >= NTILES - ti) { bid -= NTILES - ti; ti++; }
    const int tj = ti + bid;

    const int tid  = threadIdx.x;
    const int w    = tid >> 6;
    const int lane = tid & 63;
    const int half = lane >> 5;
    const int l31  = lane & 31;
    const int i0    = ti * TI;
    const int jbase = tj * TI;
    const int irow  = i0 + w * 32;

    // A fragments, full K=128 resident (8 x short8 = 64 VGPRs)
    short8 afrag[8];
#pragma unroll
    for (int ks = 0; ks < 8; ks++)
        afrag[ks] = *(const short8*)(xnb + (size_t)(irow + l31) * DK + ks * 16 + half * 8);

    int metaI[16];
    float apn[16], anc[16];
#pragma unroll
    for (int reg = 0; reg < 16; reg++) {
        int r = (reg & 3) + 8 * (reg >> 2) + 4 * half;
        metaI[reg] = meta[irow + r];
        apn[reg] = -1e9f; anc[reg] = -1e9f;
    }
    float apnC[4], ancC[4];                       // col-side accumulators, q = jt*2+ct
#pragma unroll
    for (int q = 0; q < 4; q++) { apnC[q] = -1e9f; ancC[q] = -1e9f; }

#pragma unroll
    for (int jt = 0; jt < NT; jt++) {
        const int j0 = jbase + jt * JT;

        if (jt) __syncthreads();                  // all waves done reading prior tile
        // stage tile jt (rows j0 .. j0+63); transient registers only
#pragma unroll
        for (int s = 0; s < 4; s++) {
            int chunk = tid + s * 256;
            int row = chunk >> 4, k4 = chunk & 15;
            *(uint4*)&Bs[row * BSTRH + k4 * 8] =
                *(const uint4*)(xnb + (size_t)(j0 + row) * DK + k4 * 8);
        }
        __syncthreads();

        int mjc[2];
        mjc[0] = meta[j0 + l31];
        mjc[1] = meta[j0 + 32 + l31];

#pragma unroll
        for (int ct = 0; ct < 2; ct++) {
            float16 c;
#pragma unroll
            for (int e = 0; e < 16; e++) c[e] = 0.0f;

            const int bro = ct * 32 + l31;
#pragma unroll
            for (int ks = 0; ks < 8; ks++) {
                short8 b = *(const short8*)&Bs[bro * BSTRH + ks * 16 + half * 8];
                c = __builtin_amdgcn_mfma_f32_32x32x16_bf16(afrag[ks], b, c, 0, 0, 0);
            }

            const int mj = mjc[ct];
            const int q  = jt * 2 + ct;           // compile-time (both loops unrolled)
#pragma unroll
            for (int reg = 0; reg < 16; reg++) {
                float s = c[reg];
                int x = metaI[reg] ^ mj;
                bool sl = (unsigned)x < 0x100u;   // same label
                float t8 = s - 8.0f;
                float t  = sl ? t8 : s;           // t = s - (sl?8:0)
                float negt = -t;
                apn[reg] = fmaxf(apn[reg], negt); // row-side (anchor = i)
                apnC[q]  = fmaxf(apnC[q],  negt); // col-side (anchor = j), symmetric
                bool sg = (x & 0xFFu) == 0u;      // same group
                float t4 = t + 4.0f;
                float v  = sg ? t4 : t;           // + (sg?4:0)
                anc[reg] = fmaxf(anc[reg], v);
                ancC[q]  = fmaxf(ancC[q],  v);
            }
        }
    }

    // ---- row side: butterfly reduce across the 32 column-lanes, write slot tj ----
#pragma unroll
    for (int reg = 0; reg < 16; reg++) {
#pragma unroll
        for (int off = 16; off; off >>= 1) {
            apn[reg] = fmaxf(apn[reg], __shfl_xor(apn[reg], off, 64));
            anc[reg] = fmaxf(anc[reg], __shfl_xor(anc[reg], off, 64));
        }
    }
    if (l31 == 0) {
#pragma unroll
        for (int reg = 0; reg < 16; reg++) {
            int r = (reg & 3) + 8 * (reg >> 2) + 4 * half;
            float2 o; o.x = apn[reg]; o.y = anc[reg];
            part[(size_t)tj * NB + (irow + r)] = o;
        }
    }

    // ---- col side: merge halves, cross-wave reduce via LDS, write slot ti ----
    __syncthreads();                              // all Bs reads done; safe to alias
    float* colred = (float*)&Bs[0];               // [2 arr][4 wave][4 q][32 col] = 4 KB
#pragma unroll
    for (int q = 0; q < 4; q++) {
        apnC[q] = fmaxf(apnC[q], __shfl_xor(apnC[q], 32, 64));
        ancC[q] = fmaxf(ancC[q], __shfl_xor(ancC[q], 32, 64));
        if (half == 0) {
            colred[0 * 512 + w * 128 + q * 32 + l31] = apnC[q];
            colred[1 * 512 + w * 128 + q * 32 + l31] = ancC[q];
        }
    }
    __syncthreads();
    if (tid < 128 && ti != tj) {                  // diagonal: col-side == row-side, skip
        int e = tid;                              // q*32 + col within the 128-col tile
        float ma = -1e9f, mn = -1e9f;
#pragma unroll
        for (int wv = 0; wv < 4; wv++) {
            ma = fmaxf(ma, colred[0 * 512 + wv * 128 + e]);
            mn = fmaxf(mn, colred[1 * 512 + wv * 128 + e]);
        }
        float2 o; o.x = ma; o.y = mn;
        part[(size_t)ti * NB + (jbase + e)] = o;
    }
}

// ---------------- combine all 64 valid slots + ticketed finalize ----------------
__global__ void combine_kernel(const float2* __restrict__ part,
                               float* __restrict__ accum, int* __restrict__ ticket,
                               float* __restrict__ out) {
    int i = blockIdx.x * 256 + threadIdx.x;
    float a0 = -1e9f, a1 = -1e9f, a2 = -1e9f, a3 = -1e9f;   // apn partial maxes
    float n0 = -1e9f, n1 = -1e9f, n2 = -1e9f, n3 = -1e9f;   // anc partial maxes
#pragma unroll
    for (int s = 0; s < NTILES; s += 4) {
        float2 p0 = part[(size_t)(s + 0) * NB + i];
        float2 p1 = part[(size_t)(s + 1) * NB + i];
        float2 p2 = part[(size_t)(s + 2) * NB + i];
        float2 p3 = part[(size_t)(s + 3) * NB + i];
        a0 = fmaxf(a0, p0.x); n0 = fmaxf(n0, p0.y);
        a1 = fmaxf(a1, p1.x); n1 = fmaxf(n1, p1.y);
        a2 = fmaxf(a2, p2.x); n2 = fmaxf(n2, p2.y);
        a3 = fmaxf(a3, p3.x); n3 = fmaxf(n3, p3.y);
    }
    float apn = fmaxf(fmaxf(a0, a1), fmaxf(a2, a3));
    float anc = fmaxf(fmaxf(n0, n1), fmaxf(n2, n3));

    float anS = (anc > 2.0f) ? anc - 4.0f : anc;
    // loss = anS - (8 - apn) + 0.1 ; suppressed-label values decode to loss <= 0
    float loss = anS + apn - 7.9f;
    float inc = (loss > 0.0f) ? 1.0f : 0.0f;
    float val = inc * loss;

    __shared__ float ssum[4], scnt[4];
#pragma unroll
    for (int off = 32; off; off >>= 1) {
        val += __shfl_xor(val, off, 64);
        inc += __shfl_xor(inc, off, 64);
    }
    int wid = threadIdx.x >> 6, lane = threadIdx.x & 63;
    if (lane == 0) { ssum[wid] = val; scnt[wid] = inc; }
    __syncthreads();
    if (threadIdx.x == 0) {
        float s = 0.f, c = 0.f;
#pragma unroll
        for (int wv = 0; wv < 4; wv++) { s += ssum[wv]; c += scnt[wv]; }
        atomicAdd(&accum[0], s);
        atomicAdd(&accum[1], c);
        __threadfence();                       // release: accum adds visible device-wide
        int old = atomicAdd(ticket, 1);        // device-scope
        if (old == gridDim.x - 1) {            // last block finalizes
            __threadfence();                   // acquire side
            float total = __hip_atomic_load(&accum[0], __ATOMIC_RELAXED, __HIP_MEMORY_SCOPE_AGENT);
            float cnt   = __hip_atomic_load(&accum[1], __ATOMIC_RELAXED, __HIP_MEMORY_SCOPE_AGENT);
            float r = (cnt > 0.0f) ? total / fmaxf(cnt, 1.0f) : 0.0f;
            if (isnan(r)) r = 0.0f;
            out[0] = r;
        }
    }
}

extern "C" void kernel_launch(void* const* d_in, const int* in_sizes, int n_in,
                              void* d_out, int out_size, void* d_ws, size_t ws_size,
                              hipStream_t stream) {
    const float* emb  = (const float*)d_in[0];
    const int* labels = (const int*)d_in[1];
    const int* groups = (const int*)d_in[2];
    float* out = (float*)d_out;

    unsigned short* xnb = (unsigned short*)d_ws;            // 2 MB
    int*    meta   = (int*)(xnb + (size_t)NB * DK);         // 32 KB
    float2* part   = (float2*)(meta + NB);                  // 4 MB: [64][NB] {apn,anc}
    float*  accum  = (float*)(part + (size_t)NTILES * NB);  // 2 floats
    int*    ticket = (int*)(accum + 2);                     // 1 int

    norm_kernel<<<NB / 4, 256, 0, stream>>>(emb, labels, groups, xnb, meta, accum, ticket);
    mine_tri<<<NBLK, 256, 0, stream>>>(xnb, meta, part);
    combine_kernel<<<NCOMB, 256, 0, stream>>>(part, accum, ticket, out);
}